// Round 3
// baseline (16627.307 us; speedup 1.0000x reference)
//
#include <hip/hip_runtime.h>
#include <hip/hip_bf16.h>

#define B_ 128
#define T_ 1024
#define I_ 512
#define H_ 1024
#define O_ 512
#define NBLK 256

typedef __attribute__((ext_vector_type(8))) short bf16x8;
typedef __attribute__((ext_vector_type(4))) float f32x4;
typedef unsigned short u16;

__device__ __forceinline__ unsigned f2bf_u(float f) {
  union { float f; unsigned u; } v; v.f = f;
  return (v.u + 0x7fffu + ((v.u >> 16) & 1u)) >> 16;  // RNE bf16
}

__device__ __forceinline__ bf16x8 cvt8(const float* __restrict__ p) {
  union { bf16x8 v; unsigned u[4]; } r;
  const float4 f0 = *(const float4*)p;
  const float4 f1 = *(const float4*)(p + 4);
  r.u[0] = f2bf_u(f0.x) | (f2bf_u(f0.y) << 16);
  r.u[1] = f2bf_u(f0.z) | (f2bf_u(f0.w) << 16);
  r.u[2] = f2bf_u(f1.x) | (f2bf_u(f1.y) << 16);
  r.u[3] = f2bf_u(f1.z) | (f2bf_u(f1.w) << 16);
  return r.v;
}

// Persistent RNN. Grid = 257 blocks x 256 threads.
// Blocks 0..255 compute; block 256 is a dedicated barrier aggregator.
// Compute block (bm,bn): rows r0=bm*32 (batch), cols c0=bn*16 (hidden).
// Waves K-split; W tile (16 cols x 1536 K bf16) resident in LDS all steps.
// Barrier: per-block padded flag stores (no RMW) -> aggregator -> release word.
__global__ __launch_bounds__(256) void rnn_persist(
    const float* __restrict__ x, const float* __restrict__ Wih,
    const float* __restrict__ bih, const float* __restrict__ Whh,
    const float* __restrict__ bhh, const float* __restrict__ Who,
    const float* __restrict__ bho, u16* __restrict__ h0buf,
    u16* __restrict__ h1buf, float* __restrict__ out,
    unsigned* __restrict__ release, unsigned* __restrict__ flags) {
  const int tid = threadIdx.x;

  // ---------------- aggregator block ----------------
  if (blockIdx.x == NBLK) {
    unsigned* f = flags + tid * 16;  // 64 B stride per flag
    for (int gen = 1; gen <= T_; ++gen) {
      while (__hip_atomic_load(f, __ATOMIC_RELAXED, __HIP_MEMORY_SCOPE_AGENT) <
             (unsigned)gen) {
      }
      __syncthreads();
      if (tid == 0) {
        __threadfence();
        __hip_atomic_store(release, (unsigned)gen, __ATOMIC_RELAXED,
                           __HIP_MEMORY_SCOPE_AGENT);
      }
      __syncthreads();
    }
    return;
  }

  // ---------------- compute blocks ----------------
  __shared__ u16 w_lds[192 * 16 * 8];  // 48 KB: [octet o][col c][8 bf16]
  __shared__ float red[256 * 12];      // 12 KB reduce scratch
  __shared__ float bias_lds[16];

  const int w = tid >> 6;
  const int lane = tid & 63;
  const int lr = lane & 15;
  const int kg = lane >> 4;
  const int r0 = (blockIdx.x & 3) * 32;
  const int c0 = (blockIdx.x >> 2) * 16;

  for (int idx = tid; idx < 192 * 16; idx += 256) {
    int o = idx >> 4, c = idx & 15;
    int k = o * 8, gc = c0 + c;
    const float* src = (k < H_) ? (Whh + (size_t)gc * H_ + k)
                                : (Wih + (size_t)gc * I_ + (k - H_));
    *(bf16x8*)&w_lds[idx * 8] = cvt8(src);
  }
  if (tid < 16) bias_lds[tid] = bih[c0 + tid] + bhh[c0 + tid];
  __syncthreads();

  const int redbase = (w * 64 + lane) * 12;
  const int rr = tid >> 3;
  const int cp = (tid & 7) * 2;
  const int lane_a = ((rr >> 2) & 3) << 4;
  const int jj = ((rr >> 4) << 2) + (rr & 3);

  unsigned* myflag = flags + blockIdx.x * 16;

  const f32x4 zero4 = {0.f, 0.f, 0.f, 0.f};
  f32x4 acc0 = zero4, acc1 = zero4;

  // x-part prologue for t=0
  {
    const float* px0 = x + ((size_t)(r0 + lr) * T_ + 0) * I_ + w * 128 + kg * 8;
    const float* px1 = px0 + (size_t)16 * T_ * I_;
    const u16* wb = &w_lds[((128 + w * 16 + kg) * 16 + lr) * 8];
#pragma unroll
    for (int k0 = 0; k0 < 128; k0 += 32) {
      bf16x8 a0 = cvt8(px0 + k0);
      bf16x8 a1 = cvt8(px1 + k0);
      bf16x8 b = *(const bf16x8*)(wb + (k0 >> 3) * 128);
      acc0 = __builtin_amdgcn_mfma_f32_16x16x32_bf16(a0, b, acc0, 0, 0, 0);
      acc1 = __builtin_amdgcn_mfma_f32_16x16x32_bf16(a1, b, acc1, 0, 0, 0);
    }
  }

  for (int t = 0; t < T_; ++t) {
    const u16* hc = (t & 1) ? h1buf : h0buf;
    u16* hn = (t & 1) ? h0buf : h1buf;

    // h-part: acc += h_t @ W_hh^T (K-slice per wave)
    if (t > 0) {
      const u16* pa0 = hc + (size_t)(r0 + lr) * H_ + w * 256 + kg * 8;
      const u16* pa1 = pa0 + 16 * H_;
      const u16* wb = &w_lds[((w * 32 + kg) * 16 + lr) * 8];
#pragma unroll
      for (int k0 = 0; k0 < 256; k0 += 32) {
        bf16x8 a0 = *(const bf16x8*)(pa0 + k0);
        bf16x8 a1 = *(const bf16x8*)(pa1 + k0);
        bf16x8 b = *(const bf16x8*)(wb + (k0 >> 3) * 128);
        acc0 = __builtin_amdgcn_mfma_f32_16x16x32_bf16(a0, b, acc0, 0, 0, 0);
        acc1 = __builtin_amdgcn_mfma_f32_16x16x32_bf16(a1, b, acc1, 0, 0, 0);
      }
    }

    // 4-way K-reduce via LDS, bias+relu, pack+store h_{t+1} tile
    *(f32x4*)&red[redbase] = acc0;
    *(f32x4*)&red[redbase + 4] = acc1;
    __syncthreads();
    {
      float v0 = 0.f, v1 = 0.f;
#pragma unroll
      for (int ww = 0; ww < 4; ++ww) {
        v0 += red[(ww * 64 + lane_a + cp) * 12 + jj];
        v1 += red[(ww * 64 + lane_a + cp + 1) * 12 + jj];
      }
      v0 += bias_lds[cp];
      v1 += bias_lds[cp + 1];
      v0 = v0 > 0.f ? v0 : 0.f;
      v1 = v1 > 0.f ? v1 : 0.f;
      unsigned pk = f2bf_u(v0) | (f2bf_u(v1) << 16);
      *(unsigned*)(hn + (size_t)(r0 + rr) * H_ + c0 + cp) = pk;
    }
    __syncthreads();

    // arrive: own padded flag, plain release-ordered store (no RMW)
    if (tid == 0) {
      __threadfence();
      __hip_atomic_store(myflag, (unsigned)(t + 1), __ATOMIC_RELAXED,
                         __HIP_MEMORY_SCOPE_AGENT);
    }

    // x-part for t+1 (h-independent): hides under barrier wait
    acc0 = zero4;
    acc1 = zero4;
    if (t + 1 < T_) {
      const float* px0 =
          x + ((size_t)(r0 + lr) * T_ + (t + 1)) * I_ + w * 128 + kg * 8;
      const float* px1 = px0 + (size_t)16 * T_ * I_;
      const u16* wb = &w_lds[((128 + w * 16 + kg) * 16 + lr) * 8];
#pragma unroll
      for (int k0 = 0; k0 < 128; k0 += 32) {
        bf16x8 a0 = cvt8(px0 + k0);
        bf16x8 a1 = cvt8(px1 + k0);
        bf16x8 b = *(const bf16x8*)(wb + (k0 >> 3) * 128);
        acc0 = __builtin_amdgcn_mfma_f32_16x16x32_bf16(a0, b, acc0, 0, 0, 0);
        acc1 = __builtin_amdgcn_mfma_f32_16x16x32_bf16(a1, b, acc1, 0, 0, 0);
      }
    }

    // wait for release
    if (tid == 0) {
      while (__hip_atomic_load(release, __ATOMIC_RELAXED,
                               __HIP_MEMORY_SCOPE_AGENT) < (unsigned)(t + 1))
        __builtin_amdgcn_s_sleep(1);
      __threadfence();
    }
    __syncthreads();
  }

  // output GEMM: out = h_final @ W_ho^T + b_ho (final h in h0buf)
  if (blockIdx.x < 128) {
    const int r0o = (blockIdx.x & 3) * 32;
    const int c0o = (blockIdx.x >> 2) * 16;
    f32x4 o0 = zero4, o1 = zero4;
    const u16* pa0 = h0buf + (size_t)(r0o + lr) * H_ + w * 256 + kg * 8;
    const u16* pa1 = pa0 + 16 * H_;
    const float* pwo = Who + (size_t)(c0o + lr) * H_ + w * 256 + kg * 8;
#pragma unroll
    for (int k0 = 0; k0 < 256; k0 += 32) {
      bf16x8 a0 = *(const bf16x8*)(pa0 + k0);
      bf16x8 a1 = *(const bf16x8*)(pa1 + k0);
      bf16x8 b = cvt8(pwo + k0);
      o0 = __builtin_amdgcn_mfma_f32_16x16x32_bf16(a0, b, o0, 0, 0, 0);
      o1 = __builtin_amdgcn_mfma_f32_16x16x32_bf16(a1, b, o1, 0, 0, 0);
    }
    *(f32x4*)&red[redbase] = o0;
    *(f32x4*)&red[redbase + 4] = o1;
    __syncthreads();
    float v0 = 0.f, v1 = 0.f;
#pragma unroll
    for (int ww = 0; ww < 4; ++ww) {
      v0 += red[(ww * 64 + lane_a + cp) * 12 + jj];
      v1 += red[(ww * 64 + lane_a + cp + 1) * 12 + jj];
    }
    v0 += bho[c0o + cp];
    v1 += bho[c0o + cp + 1];
    float2 st = {v0, v1};
    *(float2*)(out + (size_t)(r0o + rr) * O_ + c0o + cp) = st;
  }
}

extern "C" void kernel_launch(void* const* d_in, const int* in_sizes, int n_in,
                              void* d_out, int out_size, void* d_ws,
                              size_t ws_size, hipStream_t stream) {
  const float* x = (const float*)d_in[0];
  const float* Wih = (const float*)d_in[1];
  const float* bih = (const float*)d_in[2];
  const float* Whh = (const float*)d_in[3];
  const float* bhh = (const float*)d_in[4];
  const float* Who = (const float*)d_in[5];
  const float* bho = (const float*)d_in[6];
  float* outp = (float*)d_out;

  char* ws = (char*)d_ws;
  unsigned* release = (unsigned*)ws;                 // [0, 64)
  unsigned* flags = (unsigned*)(ws + 64);            // 256 flags x 64 B
  u16* h0b = (u16*)(ws + 32768);                     // 256 KB
  u16* h1b = (u16*)(ws + 32768 + B_ * H_ * 2);       // 256 KB

  hipMemsetAsync(ws, 0, 32768, stream);

  void* args[] = {(void*)&x,   (void*)&Wih, (void*)&bih,     (void*)&Whh,
                  (void*)&bhh, (void*)&Who, (void*)&bho,     (void*)&h0b,
                  (void*)&h1b, (void*)&outp, (void*)&release, (void*)&flags};
  hipLaunchCooperativeKernel((void*)rnn_persist, dim3(NBLK + 1), dim3(256),
                             args, 0, stream);
}

// Round 4
// 7298.765 us; speedup vs baseline: 2.2781x; 2.2781x over previous
//
#include <hip/hip_runtime.h>
#include <hip/hip_bf16.h>

#define B_ 128
#define T_ 1024
#define I_ 512
#define H_ 1024
#define O_ 512
#define NBLK 256

typedef __attribute__((ext_vector_type(8))) short bf16x8;
typedef __attribute__((ext_vector_type(4))) float f32x4;
typedef unsigned short u16;
typedef unsigned long long u64t;

__device__ __forceinline__ unsigned f2bf_u(float f) {
  union { float f; unsigned u; } v; v.f = f;
  return (v.u + 0x7fffu + ((v.u >> 16) & 1u)) >> 16;  // RNE bf16
}

__device__ __forceinline__ bf16x8 cvt8(const float* __restrict__ p) {
  union { bf16x8 v; unsigned u[4]; } r;
  const float4 f0 = *(const float4*)p;
  const float4 f1 = *(const float4*)(p + 4);
  r.u[0] = f2bf_u(f0.x) | (f2bf_u(f0.y) << 16);
  r.u[1] = f2bf_u(f0.z) | (f2bf_u(f0.w) << 16);
  r.u[2] = f2bf_u(f1.x) | (f2bf_u(f1.y) << 16);
  r.u[3] = f2bf_u(f1.z) | (f2bf_u(f1.w) << 16);
  return r.v;
}

// L2-bypassing (coherence-point) 16B load of bf16x8, via two relaxed
// agent-scope u64 atomic loads (compile to global_load_dwordx2 ... sc1).
__device__ __forceinline__ bf16x8 ld8_coh(const u16* p) {
  union { bf16x8 v; u64t q[2]; } r;
  r.q[0] = __hip_atomic_load((const u64t*)p, __ATOMIC_RELAXED,
                             __HIP_MEMORY_SCOPE_AGENT);
  r.q[1] = __hip_atomic_load((const u64t*)(p + 4), __ATOMIC_RELAXED,
                             __HIP_MEMORY_SCOPE_AGENT);
  return r.v;
}

// Persistent RNN. Grid = 257 blocks x 256 threads; block 256 = aggregator.
// Compute block (bm,bn): rows r0=bm*32 (batch), cols c0=bn*16 (hidden).
// Batch groups (bm) are independent: per-group barrier only.
// All h traffic is sc1 (L2-bypass, L3-coherent) => NO threadfence anywhere.
__global__ __launch_bounds__(256) void rnn_persist(
    const float* __restrict__ x, const float* __restrict__ Wih,
    const float* __restrict__ bih, const float* __restrict__ Whh,
    const float* __restrict__ bhh, const float* __restrict__ Who,
    const float* __restrict__ bho, u16* __restrict__ h0buf,
    u16* __restrict__ h1buf, float* __restrict__ out,
    unsigned* __restrict__ release, unsigned* __restrict__ flags) {
  const int tid = threadIdx.x;

  // ---------------- aggregator block: one wave per batch-group ----------------
  if (blockIdx.x == NBLK) {
    const int w = tid >> 6, lane = tid & 63;
    unsigned* f = flags + (lane * 4 + w) * 16;   // blockIdx = 4*bn + g
    unsigned* rel = release + w * 16;
    for (unsigned gen = 1; gen <= (unsigned)T_; ++gen) {
      for (;;) {
        unsigned v = __hip_atomic_load(f, __ATOMIC_RELAXED,
                                       __HIP_MEMORY_SCOPE_AGENT);
        if (__all(v >= gen)) break;
      }
      if (lane == 0)
        __hip_atomic_store(rel, gen, __ATOMIC_RELAXED,
                           __HIP_MEMORY_SCOPE_AGENT);
    }
    return;
  }

  // ---------------- compute blocks ----------------
  __shared__ u16 w_lds[192 * 16 * 8];  // 48 KB: [octet o][col c][8 bf16]
  __shared__ float red[256 * 12];      // 12 KB reduce scratch
  __shared__ float bias_lds[16];

  const int w = tid >> 6;
  const int lane = tid & 63;
  const int lr = lane & 15;
  const int kg = lane >> 4;
  const int grp = blockIdx.x & 3;
  const int r0 = grp * 32;
  const int c0 = (blockIdx.x >> 2) * 16;

  for (int idx = tid; idx < 192 * 16; idx += 256) {
    int o = idx >> 4, c = idx & 15;
    int k = o * 8, gc = c0 + c;
    const float* src = (k < H_) ? (Whh + (size_t)gc * H_ + k)
                                : (Wih + (size_t)gc * I_ + (k - H_));
    *(bf16x8*)&w_lds[idx * 8] = cvt8(src);
  }
  if (tid < 16) bias_lds[tid] = bih[c0 + tid] + bhh[c0 + tid];
  __syncthreads();

  const int redbase = (w * 64 + lane) * 12;
  const int rr = tid >> 3;
  const int cp = (tid & 7) * 2;
  const int lane_a = ((rr >> 2) & 3) << 4;
  const int jj = ((rr >> 4) << 2) + (rr & 3);

  unsigned* myflag = flags + blockIdx.x * 16;
  unsigned* rel_g = release + grp * 16;

  const f32x4 zero4 = {0.f, 0.f, 0.f, 0.f};
  f32x4 acc0 = zero4, acc1 = zero4;

  // x-part prologue for t=0
  {
    const float* px0 = x + ((size_t)(r0 + lr) * T_ + 0) * I_ + w * 128 + kg * 8;
    const float* px1 = px0 + (size_t)16 * T_ * I_;
    const u16* wb = &w_lds[((128 + w * 16 + kg) * 16 + lr) * 8];
#pragma unroll
    for (int k0 = 0; k0 < 128; k0 += 32) {
      bf16x8 a0 = cvt8(px0 + k0);
      bf16x8 a1 = cvt8(px1 + k0);
      bf16x8 b = *(const bf16x8*)(wb + (k0 >> 3) * 128);
      acc0 = __builtin_amdgcn_mfma_f32_16x16x32_bf16(a0, b, acc0, 0, 0, 0);
      acc1 = __builtin_amdgcn_mfma_f32_16x16x32_bf16(a1, b, acc1, 0, 0, 0);
    }
  }

  for (int t = 0; t < T_; ++t) {
    const u16* hc = (t & 1) ? h1buf : h0buf;
    u16* hn = (t & 1) ? h0buf : h1buf;

    // h-part: acc += h_t @ W_hh^T (K-slice per wave), sc1 loads
    if (t > 0) {
      const u16* pa0 = hc + (size_t)(r0 + lr) * H_ + w * 256 + kg * 8;
      const u16* pa1 = pa0 + 16 * H_;
      const u16* wb = &w_lds[((w * 32 + kg) * 16 + lr) * 8];
#pragma unroll
      for (int k0 = 0; k0 < 256; k0 += 32) {
        bf16x8 a0 = ld8_coh(pa0 + k0);
        bf16x8 a1 = ld8_coh(pa1 + k0);
        bf16x8 b = *(const bf16x8*)(wb + (k0 >> 3) * 128);
        acc0 = __builtin_amdgcn_mfma_f32_16x16x32_bf16(a0, b, acc0, 0, 0, 0);
        acc1 = __builtin_amdgcn_mfma_f32_16x16x32_bf16(a1, b, acc1, 0, 0, 0);
      }
    }

    // 4-way K-reduce via LDS, bias+relu, pack + sc1 store of h_{t+1} tile
    *(f32x4*)&red[redbase] = acc0;
    *(f32x4*)&red[redbase + 4] = acc1;
    __syncthreads();
    {
      float v0 = 0.f, v1 = 0.f;
#pragma unroll
      for (int ww = 0; ww < 4; ++ww) {
        v0 += red[(ww * 64 + lane_a + cp) * 12 + jj];
        v1 += red[(ww * 64 + lane_a + cp + 1) * 12 + jj];
      }
      v0 += bias_lds[cp];
      v1 += bias_lds[cp + 1];
      v0 = v0 > 0.f ? v0 : 0.f;
      v1 = v1 > 0.f ? v1 : 0.f;
      unsigned pk = f2bf_u(v0) | (f2bf_u(v1) << 16);
      __hip_atomic_store((unsigned*)(hn + (size_t)(r0 + rr) * H_ + c0 + cp),
                         pk, __ATOMIC_RELAXED, __HIP_MEMORY_SCOPE_AGENT);
    }
    // barrier drains each wave's vmcnt before s_barrier => all sc1 stores
    // are at the coherence point before the flag store below. No fence.
    __syncthreads();

    if (tid == 0)
      __hip_atomic_store(myflag, (unsigned)(t + 1), __ATOMIC_RELAXED,
                         __HIP_MEMORY_SCOPE_AGENT);

    // x-part for t+1 (h-independent): hides under barrier wait
    acc0 = zero4;
    acc1 = zero4;
    if (t + 1 < T_) {
      const float* px0 =
          x + ((size_t)(r0 + lr) * T_ + (t + 1)) * I_ + w * 128 + kg * 8;
      const float* px1 = px0 + (size_t)16 * T_ * I_;
      const u16* wb = &w_lds[((128 + w * 16 + kg) * 16 + lr) * 8];
#pragma unroll
      for (int k0 = 0; k0 < 128; k0 += 32) {
        bf16x8 a0 = cvt8(px0 + k0);
        bf16x8 a1 = cvt8(px1 + k0);
        bf16x8 b = *(const bf16x8*)(wb + (k0 >> 3) * 128);
        acc0 = __builtin_amdgcn_mfma_f32_16x16x32_bf16(a0, b, acc0, 0, 0, 0);
        acc1 = __builtin_amdgcn_mfma_f32_16x16x32_bf16(a1, b, acc1, 0, 0, 0);
      }
    }

    // wait for this group's release (no fence; sc1 poll)
    if (tid == 0) {
      while (__hip_atomic_load(rel_g, __ATOMIC_RELAXED,
                               __HIP_MEMORY_SCOPE_AGENT) < (unsigned)(t + 1))
        __builtin_amdgcn_s_sleep(1);
    }
    __syncthreads();
  }

  // output GEMM: out = h_final @ W_ho^T + b_ho (final h in h0buf), sc1 reads
  if (blockIdx.x < 128) {
    const int r0o = (blockIdx.x & 3) * 32;
    const int c0o = (blockIdx.x >> 2) * 16;
    f32x4 o0 = zero4, o1 = zero4;
    const u16* pa0 = h0buf + (size_t)(r0o + lr) * H_ + w * 256 + kg * 8;
    const u16* pa1 = pa0 + 16 * H_;
    const float* pwo = Who + (size_t)(c0o + lr) * H_ + w * 256 + kg * 8;
#pragma unroll
    for (int k0 = 0; k0 < 256; k0 += 32) {
      bf16x8 a0 = ld8_coh(pa0 + k0);
      bf16x8 a1 = ld8_coh(pa1 + k0);
      bf16x8 b = cvt8(pwo + k0);
      o0 = __builtin_amdgcn_mfma_f32_16x16x32_bf16(a0, b, o0, 0, 0, 0);
      o1 = __builtin_amdgcn_mfma_f32_16x16x32_bf16(a1, b, o1, 0, 0, 0);
    }
    *(f32x4*)&red[redbase] = o0;
    *(f32x4*)&red[redbase + 4] = o1;
    __syncthreads();
    float v0 = 0.f, v1 = 0.f;
#pragma unroll
    for (int ww = 0; ww < 4; ++ww) {
      v0 += red[(ww * 64 + lane_a + cp) * 12 + jj];
      v1 += red[(ww * 64 + lane_a + cp + 1) * 12 + jj];
    }
    v0 += bho[c0o + cp];
    v1 += bho[c0o + cp + 1];
    float2 st = {v0, v1};
    *(float2*)(out + (size_t)(r0o + rr) * O_ + c0o + cp) = st;
  }
}

extern "C" void kernel_launch(void* const* d_in, const int* in_sizes, int n_in,
                              void* d_out, int out_size, void* d_ws,
                              size_t ws_size, hipStream_t stream) {
  const float* x = (const float*)d_in[0];
  const float* Wih = (const float*)d_in[1];
  const float* bih = (const float*)d_in[2];
  const float* Whh = (const float*)d_in[3];
  const float* bhh = (const float*)d_in[4];
  const float* Who = (const float*)d_in[5];
  const float* bho = (const float*)d_in[6];
  float* outp = (float*)d_out;

  char* ws = (char*)d_ws;
  unsigned* release = (unsigned*)ws;                 // 4 words x 64 B
  unsigned* flags = (unsigned*)(ws + 1024);          // 256 flags x 64 B
  u16* h0b = (u16*)(ws + 32768);                     // 256 KB
  u16* h1b = (u16*)(ws + 32768 + B_ * H_ * 2);       // 256 KB

  hipMemsetAsync(ws, 0, 32768, stream);

  void* args[] = {(void*)&x,   (void*)&Wih, (void*)&bih,     (void*)&Whh,
                  (void*)&bhh, (void*)&Who, (void*)&bho,     (void*)&h0b,
                  (void*)&h1b, (void*)&outp, (void*)&release, (void*)&flags};
  hipLaunchCooperativeKernel((void*)rnn_persist, dim3(NBLK + 1), dim3(256),
                             args, 0, stream);
}

// Round 6
// 4215.853 us; speedup vs baseline: 3.9440x; 1.7313x over previous
//
#include <hip/hip_runtime.h>
#include <hip/hip_bf16.h>

#define B_ 128
#define T_ 1024
#define I_ 512
#define H_ 1024
#define O_ 512
#define NBLK 256

typedef __attribute__((ext_vector_type(8))) short bf16x8;
typedef __attribute__((ext_vector_type(4))) float f32x4;
typedef unsigned short u16;
typedef unsigned long long u64t;

__device__ __forceinline__ unsigned f2bf_u(float f) {
  union { float f; unsigned u; } v; v.f = f;
  return (v.u + 0x7fffu + ((v.u >> 16) & 1u)) >> 16;  // RNE bf16
}

__device__ __forceinline__ bf16x8 cvt8(const float* __restrict__ p) {
  union { bf16x8 v; unsigned u[4]; } r;
  const float4 f0 = *(const float4*)p;
  const float4 f1 = *(const float4*)(p + 4);
  r.u[0] = f2bf_u(f0.x) | (f2bf_u(f0.y) << 16);
  r.u[1] = f2bf_u(f0.z) | (f2bf_u(f0.w) << 16);
  r.u[2] = f2bf_u(f1.x) | (f2bf_u(f1.y) << 16);
  r.u[3] = f2bf_u(f1.z) | (f2bf_u(f1.w) << 16);
  return r.v;
}

__device__ __forceinline__ bf16x8 cvt8r(float4 f0, float4 f1) {
  union { bf16x8 v; unsigned u[4]; } r;
  r.u[0] = f2bf_u(f0.x) | (f2bf_u(f0.y) << 16);
  r.u[1] = f2bf_u(f0.z) | (f2bf_u(f0.w) << 16);
  r.u[2] = f2bf_u(f1.x) | (f2bf_u(f1.y) << 16);
  r.u[3] = f2bf_u(f1.z) | (f2bf_u(f1.w) << 16);
  return r.v;
}

// L3-coherent 16B load (sc1, bypasses non-coherent caches) — proven in round 4.
__device__ __forceinline__ bf16x8 ld8_coh(const u16* p) {
  union { bf16x8 v; u64t q[2]; } r;
  r.q[0] = __hip_atomic_load((const u64t*)p, __ATOMIC_RELAXED,
                             __HIP_MEMORY_SCOPE_AGENT);
  r.q[1] = __hip_atomic_load((const u64t*)(p + 4), __ATOMIC_RELAXED,
                             __HIP_MEMORY_SCOPE_AGENT);
  return r.v;
}

#define MFMA __builtin_amdgcn_mfma_f32_16x16x32_bf16

// Persistent RNN. Grid = 256 blocks x 256 threads (4 waves), 1 block/CU.
// Group g = blockIdx>>5 (16 batch rows); slot s = blockIdx&31 (32 hidden cols).
// W tile (32 cols x 1536 K bf16, 96 KB) resident in LDS. Waves K-split 4-way.
// Sync: per-(producer,wave) flags, sc1, polled directly by consumers. No
// aggregator, no global barrier, no fences. Flags monotone => deadlock-free.
__global__ __launch_bounds__(256, 1) void rnn_persist(
    const float* __restrict__ x, const float* __restrict__ Wih,
    const float* __restrict__ bih, const float* __restrict__ Whh,
    const float* __restrict__ bhh, const float* __restrict__ Who,
    const float* __restrict__ bho, u16* __restrict__ h0buf,
    u16* __restrict__ h1buf, float* __restrict__ out,
    unsigned* __restrict__ flags) {
  __shared__ u16 w_lds[192 * 32 * 8];  // 96 KB: [k-octet o][col c][8 bf16]
  __shared__ float red[2][256 * 9];    // 18 KB double-buffered reduce scratch
  __shared__ float bias_lds[32];

  const int tid = threadIdx.x;
  const int w = tid >> 6;
  const int lane = tid & 63;
  const int lr = lane & 15;
  const int kg = lane >> 4;
  const int g = (int)blockIdx.x >> 5;
  const int s = (int)blockIdx.x & 31;
  const int r0 = g * 16;
  const int c0 = s * 32;

  // ---- stage W tile [32 cols x 1536 K] into LDS ----
  for (int e = tid; e < 192 * 32; e += 256) {
    int o = e >> 5, c = e & 31;
    int k = o * 8, gc = c0 + c;
    const float* src = (k < H_) ? (Whh + (size_t)gc * H_ + k)
                                : (Wih + (size_t)gc * I_ + (k - H_));
    *(bf16x8*)&w_lds[e * 8] = cvt8(src);
  }
  if (tid < 32) bias_lds[tid] = bih[c0 + tid] + bhh[c0 + tid];
  __syncthreads();

  // LDS fragment bases (u16 units)
  const u16* wb_h = &w_lds[(((w * 32 + kg) * 32) + lr) * 8];
  const u16* wb_x = &w_lds[(((128 + w * 16 + kg) * 32) + lr) * 8];

  // flags: 64 B per producer slot; 4 wave-flags at +0,+16,+32,+48 (u32 units)
  unsigned* flagbase = flags + g * 32 * 16;
  unsigned* myflag = flagbase + s * 16 + w * 4;
  // this wave consumes producers p = w*8..w*8+7; lane polls (p, wv):
  unsigned* pollp = flagbase + (w * 8 + ((lane >> 2) & 7)) * 16 + (lane & 3) * 4;

  // reduce/store thread mapping
  const int rr = tid >> 4;           // row 0..15
  const int cpair = (tid & 15) * 2;  // col pair 0,2,..,30
  const int lane_r = (rr >> 2) << 4;
  const int reg_r = rr & 3;

  const f32x4 zero4 = {0.f, 0.f, 0.f, 0.f};
  f32x4 acc0, acc1, xacc0, xacc1;

  // ---- prologue: x-part for t=0 into acc ----
  {
    const float* px = x + ((size_t)(r0 + lr) * T_) * I_ + w * 128 + kg * 8;
    acc0 = zero4;
    acc1 = zero4;
#pragma unroll
    for (int i = 0; i < 4; ++i) {
      bf16x8 a = cvt8(px + i * 32);
      acc0 = MFMA(a, *(const bf16x8*)(wb_x + i * 1024), acc0, 0, 0, 0);
      acc1 = MFMA(a, *(const bf16x8*)(wb_x + i * 1024 + 128), acc1, 0, 0, 0);
    }
  }

  for (int t = 0; t < T_; ++t) {
    const u16* hc = (t & 1) ? h1buf : h0buf;
    u16* hn = (t & 1) ? h0buf : h1buf;
    const bool havex = (t + 1 < T_);

    // C1: issue x loads for t+1 early (independent of h)
    float4 xa0, xa1, xa2, xa3, xa4, xa5, xa6, xa7;
    const float* px =
        x + ((size_t)(r0 + lr) * T_ + (t + 1)) * I_ + w * 128 + kg * 8;
    if (havex) {
      xa0 = *(const float4*)(px);      xa1 = *(const float4*)(px + 4);
      xa2 = *(const float4*)(px + 32); xa3 = *(const float4*)(px + 36);
      xa4 = *(const float4*)(px + 64); xa5 = *(const float4*)(px + 68);
      xa6 = *(const float4*)(px + 96); xa7 = *(const float4*)(px + 100);
    }

    xacc0 = zero4;
    xacc1 = zero4;

    if (t > 0) {
      // A: poll the 8 producers' 4 wave-flags (32 flags, 1 load/lane/iter)
      while (!__all((int)(__hip_atomic_load(pollp, __ATOMIC_RELAXED,
                                            __HIP_MEMORY_SCOPE_AGENT) >=
                          (unsigned)t))) {
      }
      // B: issue all 16 sc1 h loads (8 slices x 16 B)
      const u16* pa = hc + (size_t)(r0 + lr) * H_ + w * 256 + kg * 8;
      bf16x8 hs0 = ld8_coh(pa);
      bf16x8 hs1 = ld8_coh(pa + 32);
      bf16x8 hs2 = ld8_coh(pa + 64);
      bf16x8 hs3 = ld8_coh(pa + 96);
      bf16x8 hs4 = ld8_coh(pa + 128);
      bf16x8 hs5 = ld8_coh(pa + 160);
      bf16x8 hs6 = ld8_coh(pa + 192);
      bf16x8 hs7 = ld8_coh(pa + 224);
      // C2: x-part for t+1 (xa already returned during poll — no VMEM wait)
      if (havex) {
        bf16x8 a0 = cvt8r(xa0, xa1), a1 = cvt8r(xa2, xa3);
        bf16x8 a2 = cvt8r(xa4, xa5), a3 = cvt8r(xa6, xa7);
        xacc0 = MFMA(a0, *(const bf16x8*)(wb_x), xacc0, 0, 0, 0);
        xacc1 = MFMA(a0, *(const bf16x8*)(wb_x + 128), xacc1, 0, 0, 0);
        xacc0 = MFMA(a1, *(const bf16x8*)(wb_x + 1024), xacc0, 0, 0, 0);
        xacc1 = MFMA(a1, *(const bf16x8*)(wb_x + 1152), xacc1, 0, 0, 0);
        xacc0 = MFMA(a2, *(const bf16x8*)(wb_x + 2048), xacc0, 0, 0, 0);
        xacc1 = MFMA(a2, *(const bf16x8*)(wb_x + 2176), xacc1, 0, 0, 0);
        xacc0 = MFMA(a3, *(const bf16x8*)(wb_x + 3072), xacc0, 0, 0, 0);
        xacc1 = MFMA(a3, *(const bf16x8*)(wb_x + 3200), xacc1, 0, 0, 0);
      }
      // D: h-part MFMAs (consume hs as they return, in order)
#define HS(i, hv)                                                       \
  acc0 = MFMA(hv, *(const bf16x8*)(wb_h + (i)*1024), acc0, 0, 0, 0);    \
  acc1 = MFMA(hv, *(const bf16x8*)(wb_h + (i)*1024 + 128), acc1, 0, 0, 0);
      HS(0, hs0) HS(1, hs1) HS(2, hs2) HS(3, hs3)
      HS(4, hs4) HS(5, hs5) HS(6, hs6) HS(7, hs7)
#undef HS
    } else if (havex) {
      bf16x8 a0 = cvt8r(xa0, xa1), a1 = cvt8r(xa2, xa3);
      bf16x8 a2 = cvt8r(xa4, xa5), a3 = cvt8r(xa6, xa7);
      xacc0 = MFMA(a0, *(const bf16x8*)(wb_x), xacc0, 0, 0, 0);
      xacc1 = MFMA(a0, *(const bf16x8*)(wb_x + 128), xacc1, 0, 0, 0);
      xacc0 = MFMA(a1, *(const bf16x8*)(wb_x + 1024), xacc0, 0, 0, 0);
      xacc1 = MFMA(a1, *(const bf16x8*)(wb_x + 1152), xacc1, 0, 0, 0);
      xacc0 = MFMA(a2, *(const bf16x8*)(wb_x + 2048), xacc0, 0, 0, 0);
      xacc1 = MFMA(a2, *(const bf16x8*)(wb_x + 2176), xacc1, 0, 0, 0);
      xacc0 = MFMA(a3, *(const bf16x8*)(wb_x + 3072), xacc0, 0, 0, 0);
      xacc1 = MFMA(a3, *(const bf16x8*)(wb_x + 3200), xacc1, 0, 0, 0);
    }

    // E: cross-wave K-reduce staging (double-buffered red, one barrier)
    float* redc = red[t & 1];
    *(f32x4*)&redc[(w * 64 + lane) * 9] = acc0;
    *(f32x4*)&redc[(w * 64 + lane) * 9 + 4] = acc1;
    __syncthreads();

    // F: reduce + bias + relu, pack, sc1-store tile rows; per-wave publish
    {
      const int c1 = cpair + 1;
      const int l0 = lane_r | (cpair & 15), f0 = (cpair >> 4) * 4;
      const int l1 = lane_r | (c1 & 15), f1 = (c1 >> 4) * 4;
      float v0 = 0.f, v1 = 0.f;
#pragma unroll
      for (int ww = 0; ww < 4; ++ww) {
        v0 += redc[(ww * 64 + l0) * 9 + f0 + reg_r];
        v1 += redc[(ww * 64 + l1) * 9 + f1 + reg_r];
      }
      v0 += bias_lds[cpair];
      v1 += bias_lds[c1];
      v0 = fmaxf(v0, 0.f);
      v1 = fmaxf(v1, 0.f);
      unsigned pk = f2bf_u(v0) | (f2bf_u(v1) << 16);
      __hip_atomic_store((unsigned*)(hn + (size_t)(r0 + rr) * H_ + c0 + cpair),
                         pk, __ATOMIC_RELAXED, __HIP_MEMORY_SCOPE_AGENT);
    }
    // wave w stored exactly rows w*4..w*4+3; drain own stores, publish flag
    asm volatile("s_waitcnt vmcnt(0)" ::: "memory");
    if (lane == 0)
      __hip_atomic_store(myflag, (unsigned)(t + 1), __ATOMIC_RELAXED,
                         __HIP_MEMORY_SCOPE_AGENT);

    // G: promote next-step x-part
    acc0 = xacc0;
    acc1 = xacc1;
  }

  // ---- wait for whole group at gen T, then output GEMM ----
  {
    unsigned* q0 = flagbase + (lane >> 2) * 16 + (lane & 3) * 4;  // p 0..15
    unsigned* q1 = q0 + 16 * 16;                                  // p 16..31
    while (!__all((int)((__hip_atomic_load(q0, __ATOMIC_RELAXED,
                                           __HIP_MEMORY_SCOPE_AGENT) >=
                         (unsigned)T_) &
                        (__hip_atomic_load(q1, __ATOMIC_RELAXED,
                                           __HIP_MEMORY_SCOPE_AGENT) >=
                         (unsigned)T_)))) {
    }
  }
  {
    // out[16 rows x 16 cols] = h_final @ Who^T + bho ; final h in h0buf
    const int c0o = s * 16;
    f32x4 o0 = zero4;
    const u16* pa = h0buf + (size_t)(r0 + lr) * H_ + w * 256 + kg * 8;
    const float* pwo = Who + (size_t)(c0o + lr) * H_ + w * 256 + kg * 8;
#pragma unroll
    for (int i = 0; i < 8; ++i) {
      bf16x8 a = ld8_coh(pa + i * 32);
      bf16x8 b = cvt8(pwo + i * 32);
      o0 = MFMA(a, b, o0, 0, 0, 0);
    }
    float* redc = red[0];
    *(f32x4*)&redc[(w * 64 + lane) * 9] = o0;
    __syncthreads();
    const int cc = tid & 15;
    const int l0 = lane_r | cc;
    float v = 0.f;
#pragma unroll
    for (int ww = 0; ww < 4; ++ww) v += redc[(ww * 64 + l0) * 9 + reg_r];
    v += bho[c0o + cc];
    out[(size_t)(r0 + rr) * O_ + c0o + cc] = v;
  }
}

extern "C" void kernel_launch(void* const* d_in, const int* in_sizes, int n_in,
                              void* d_out, int out_size, void* d_ws,
                              size_t ws_size, hipStream_t stream) {
  const float* x = (const float*)d_in[0];
  const float* Wih = (const float*)d_in[1];
  const float* bih = (const float*)d_in[2];
  const float* Whh = (const float*)d_in[3];
  const float* bhh = (const float*)d_in[4];
  const float* Who = (const float*)d_in[5];
  const float* bho = (const float*)d_in[6];
  float* outp = (float*)d_out;

  char* ws = (char*)d_ws;
  unsigned* flags = (unsigned*)ws;                   // 256 slots x 64 B = 16 KB
  u16* h0b = (u16*)(ws + 16384);                     // 256 KB
  u16* h1b = (u16*)(ws + 16384 + B_ * H_ * 2);       // 256 KB

  hipMemsetAsync(flags, 0, 16384, stream);

  void* args[] = {(void*)&x,   (void*)&Wih, (void*)&bih, (void*)&Whh,
                  (void*)&bhh, (void*)&Who, (void*)&bho, (void*)&h0b,
                  (void*)&h1b, (void*)&outp, (void*)&flags};
  hipLaunchCooperativeKernel((void*)rnn_persist, dim3(NBLK), dim3(256), args,
                             0, stream);
}

// Round 7
// 4056.879 us; speedup vs baseline: 4.0985x; 1.0392x over previous
//
#include <hip/hip_runtime.h>
#include <hip/hip_bf16.h>

#define B_ 128
#define T_ 1024
#define I_ 512
#define H_ 1024
#define O_ 512
#define NBLK 256

typedef __attribute__((ext_vector_type(8))) short bf16x8;
typedef __attribute__((ext_vector_type(4))) float f32x4;
typedef unsigned short u16;
typedef unsigned long long u64t;

#define TAGMASK 0x8000800080008000ull

__device__ __forceinline__ unsigned f2bf_u(float f) {
  union { float f; unsigned u; } v; v.f = f;
  return (v.u + 0x7fffu + ((v.u >> 16) & 1u)) >> 16;  // RNE bf16
}

__device__ __forceinline__ bf16x8 cvt8(const float* __restrict__ p) {
  union { bf16x8 v; unsigned u[4]; } r;
  const float4 f0 = *(const float4*)p;
  const float4 f1 = *(const float4*)(p + 4);
  r.u[0] = f2bf_u(f0.x) | (f2bf_u(f0.y) << 16);
  r.u[1] = f2bf_u(f0.z) | (f2bf_u(f0.w) << 16);
  r.u[2] = f2bf_u(f1.x) | (f2bf_u(f1.y) << 16);
  r.u[3] = f2bf_u(f1.z) | (f2bf_u(f1.w) << 16);
  return r.v;
}

__device__ __forceinline__ bf16x8 cvt8r(float4 f0, float4 f1) {
  union { bf16x8 v; unsigned u[4]; } r;
  r.u[0] = f2bf_u(f0.x) | (f2bf_u(f0.y) << 16);
  r.u[1] = f2bf_u(f0.z) | (f2bf_u(f0.w) << 16);
  r.u[2] = f2bf_u(f1.x) | (f2bf_u(f1.y) << 16);
  r.u[3] = f2bf_u(f1.z) | (f2bf_u(f1.w) << 16);
  return r.v;
}

// agent-scope (sc1, L3-coherent) u64 load — round-4-proven primitive
__device__ __forceinline__ u64t ld64(const u64t* p) {
  return __hip_atomic_load(p, __ATOMIC_RELAXED, __HIP_MEMORY_SCOPE_AGENT);
}

// two tag-validated u64 halves -> sign-cleared bf16x8
__device__ __forceinline__ bf16x8 mk8(u64t lo, u64t hi) {
  union { u64t q[2]; bf16x8 b; } v;
  v.q[0] = lo & ~TAGMASK;
  v.q[1] = hi & ~TAGMASK;
  return v.b;
}

#define MFMA __builtin_amdgcn_mfma_f32_16x16x32_bf16

// Persistent RNN. Grid = 256 blocks x 256 threads (4 waves), 1 block/CU.
// Group g = blockIdx>>5 (16 batch rows); slot s = blockIdx&31 (32 hidden cols).
// W tile (32 cols x 1536 K bf16, 96 KB) resident in LDS. Waves K-split 4-way.
// Sync: NO flags. Generation tag ((s>>1)&1) embedded in the (always-zero
// after relu) bf16 sign bits of h itself; consumers poll the data until all
// words carry the expected tag, then clear signs. Monotone => deadlock-free.
__global__ __launch_bounds__(256, 1) void rnn_persist(
    const float* __restrict__ x, const float* __restrict__ Wih,
    const float* __restrict__ bih, const float* __restrict__ Whh,
    const float* __restrict__ bhh, const float* __restrict__ Who,
    const float* __restrict__ bho, u16* __restrict__ h0buf,
    u16* __restrict__ h1buf, float* __restrict__ out) {
  __shared__ u16 w_lds[192 * 32 * 8];  // 96 KB: [k-octet o][col c][8 bf16]
  __shared__ float red[256 * 9];       // 9 KB reduce scratch (stride 9)
  __shared__ float bias_lds[32];

  const int tid = threadIdx.x;
  const int w = tid >> 6;
  const int lane = tid & 63;
  const int lr = lane & 15;
  const int kg = lane >> 4;
  const int g = (int)blockIdx.x >> 5;
  const int s = (int)blockIdx.x & 31;
  const int r0 = g * 16;
  const int c0 = s * 32;

  // ---- stage W tile [32 cols x 1536 K] into LDS ----
  for (int e = tid; e < 192 * 32; e += 256) {
    int o = e >> 5, c = e & 31;
    int k = o * 8, gc = c0 + c;
    const float* src = (k < H_) ? (Whh + (size_t)gc * H_ + k)
                                : (Wih + (size_t)gc * I_ + (k - H_));
    *(bf16x8*)&w_lds[e * 8] = cvt8(src);
  }
  if (tid < 32) bias_lds[tid] = bih[c0 + tid] + bhh[c0 + tid];
  __syncthreads();

  // LDS fragment bases (u16 units)
  const u16* wb_h = &w_lds[(((w * 32 + kg) * 32) + lr) * 8];
  const u16* wb_x = &w_lds[(((128 + w * 16 + kg) * 32) + lr) * 8];

  // reduce/store thread mapping
  const int rr = tid >> 4;           // row 0..15
  const int cpair = (tid & 15) * 2;  // col pair 0,2,..,30
  const int lane_r = (rr >> 2) << 4;
  const int reg_r = rr & 3;

  const f32x4 zero4 = {0.f, 0.f, 0.f, 0.f};
  f32x4 acc0, acc1;

  // ---- prologue: x-part for t=0 into acc ----
  {
    const float* px = x + ((size_t)(r0 + lr) * T_) * I_ + w * 128 + kg * 8;
    acc0 = zero4;
    acc1 = zero4;
#pragma unroll
    for (int i = 0; i < 4; ++i) {
      bf16x8 a = cvt8(px + i * 32);
      acc0 = MFMA(a, *(const bf16x8*)(wb_x + i * 1024), acc0, 0, 0, 0);
      acc1 = MFMA(a, *(const bf16x8*)(wb_x + i * 1024 + 128), acc1, 0, 0, 0);
    }
  }

  for (int t = 0; t < T_; ++t) {
    const u16* hc = (t & 1) ? h1buf : h0buf;
    u16* hn = (t & 1) ? h0buf : h1buf;
    const bool havex = (t + 1 < T_);

    // 1: issue x loads for t+1 early (independent of h)
    float4 xa0, xa1, xa2, xa3, xa4, xa5, xa6, xa7;
    const float* px =
        x + ((size_t)(r0 + lr) * T_ + (t + 1)) * I_ + w * 128 + kg * 8;
    if (havex) {
      xa0 = *(const float4*)(px);      xa1 = *(const float4*)(px + 4);
      xa2 = *(const float4*)(px + 32); xa3 = *(const float4*)(px + 36);
      xa4 = *(const float4*)(px + 64); xa5 = *(const float4*)(px + 68);
      xa6 = *(const float4*)(px + 96); xa7 = *(const float4*)(px + 100);
    }

    // 2: tag-poll h_t (the poll IS the load), then h-MFMAs
    if (t > 0) {
      const u64t twq = ((t >> 1) & 1) ? TAGMASK : 0ull;
      const u64t* pa =
          (const u64t*)(hc + (size_t)(r0 + lr) * H_ + w * 256 + kg * 8);
      u64t q0, q1, q2, q3, q4, q5, q6, q7;
      u64t q8, q9, qa, qb, qc, qd, qe, qf;
      for (;;) {
        q0 = ld64(pa + 0);  q1 = ld64(pa + 1);   // chunk 0 (k-octet kg)
        q2 = ld64(pa + 8);  q3 = ld64(pa + 9);   // chunk 1 (kg+4)
        q4 = ld64(pa + 16); q5 = ld64(pa + 17);
        q6 = ld64(pa + 24); q7 = ld64(pa + 25);
        q8 = ld64(pa + 32); q9 = ld64(pa + 33);
        qa = ld64(pa + 40); qb = ld64(pa + 41);
        qc = ld64(pa + 48); qd = ld64(pa + 49);
        qe = ld64(pa + 56); qf = ld64(pa + 57);
        u64t m = (q0 ^ twq) | (q1 ^ twq) | (q2 ^ twq) | (q3 ^ twq) |
                 (q4 ^ twq) | (q5 ^ twq) | (q6 ^ twq) | (q7 ^ twq) |
                 (q8 ^ twq) | (q9 ^ twq) | (qa ^ twq) | (qb ^ twq) |
                 (qc ^ twq) | (qd ^ twq) | (qe ^ twq) | (qf ^ twq);
        if (__all((m & TAGMASK) == 0ull)) break;
      }
#define HS(i, hv)                                                      \
  acc0 = MFMA(hv, *(const bf16x8*)(wb_h + (i)*1024), acc0, 0, 0, 0);   \
  acc1 = MFMA(hv, *(const bf16x8*)(wb_h + (i)*1024 + 128), acc1, 0, 0, 0);
      HS(0, mk8(q0, q1)) HS(1, mk8(q2, q3))
      HS(2, mk8(q4, q5)) HS(3, mk8(q6, q7))
      HS(4, mk8(q8, q9)) HS(5, mk8(qa, qb))
      HS(6, mk8(qc, qd)) HS(7, mk8(qe, qf))
#undef HS
    }

    // 3: cross-wave K-reduce, bias+relu, pack + tag, sc1 store (NO drain)
    *(f32x4*)&red[(w * 64 + lane) * 9] = acc0;
    *(f32x4*)&red[(w * 64 + lane) * 9 + 4] = acc1;
    __syncthreads();
    {
      const unsigned st = (((t + 1) >> 1) & 1) ? 0x80008000u : 0u;
      const int c1 = cpair + 1;
      const int l0 = lane_r | (cpair & 15), f0 = (cpair >> 4) * 4;
      const int l1 = lane_r | (c1 & 15), f1 = (c1 >> 4) * 4;
      float v0 = 0.f, v1 = 0.f;
#pragma unroll
      for (int ww = 0; ww < 4; ++ww) {
        v0 += red[(ww * 64 + l0) * 9 + f0 + reg_r];
        v1 += red[(ww * 64 + l1) * 9 + f1 + reg_r];
      }
      v0 += bias_lds[cpair];
      v1 += bias_lds[c1];
      v0 = v0 > 0.f ? v0 : 0.f;  // ternary: +0 always (no -0 sign pollution)
      v1 = v1 > 0.f ? v1 : 0.f;
      unsigned pk = (f2bf_u(v0) | (f2bf_u(v1) << 16)) | st;
      __hip_atomic_store((unsigned*)(hn + (size_t)(r0 + rr) * H_ + c0 + cpair),
                         pk, __ATOMIC_RELAXED, __HIP_MEMORY_SCOPE_AGENT);
    }

    // 4: x-part for t+1 (off critical path; overlaps consumers' polls)
    f32x4 xacc0 = zero4, xacc1 = zero4;
    if (havex) {
      bf16x8 a0 = cvt8r(xa0, xa1), a1 = cvt8r(xa2, xa3);
      bf16x8 a2 = cvt8r(xa4, xa5), a3 = cvt8r(xa6, xa7);
      xacc0 = MFMA(a0, *(const bf16x8*)(wb_x), xacc0, 0, 0, 0);
      xacc1 = MFMA(a0, *(const bf16x8*)(wb_x + 128), xacc1, 0, 0, 0);
      xacc0 = MFMA(a1, *(const bf16x8*)(wb_x + 1024), xacc0, 0, 0, 0);
      xacc1 = MFMA(a1, *(const bf16x8*)(wb_x + 1152), xacc1, 0, 0, 0);
      xacc0 = MFMA(a2, *(const bf16x8*)(wb_x + 2048), xacc0, 0, 0, 0);
      xacc1 = MFMA(a2, *(const bf16x8*)(wb_x + 2176), xacc1, 0, 0, 0);
      xacc0 = MFMA(a3, *(const bf16x8*)(wb_x + 3072), xacc0, 0, 0, 0);
      xacc1 = MFMA(a3, *(const bf16x8*)(wb_x + 3200), xacc1, 0, 0, 0);
    }
    acc0 = xacc0;
    acc1 = xacc1;
  }

  // ---- output GEMM: poll h_T (tag 0) then out = h @ Who^T + bho ----
  {
    const u64t* pa =
        (const u64t*)(h0buf + (size_t)(r0 + lr) * H_ + w * 256 + kg * 8);
    u64t q0, q1, q2, q3, q4, q5, q6, q7;
    u64t q8, q9, qa, qb, qc, qd, qe, qf;
    for (;;) {
      q0 = ld64(pa + 0);  q1 = ld64(pa + 1);
      q2 = ld64(pa + 8);  q3 = ld64(pa + 9);
      q4 = ld64(pa + 16); q5 = ld64(pa + 17);
      q6 = ld64(pa + 24); q7 = ld64(pa + 25);
      q8 = ld64(pa + 32); q9 = ld64(pa + 33);
      qa = ld64(pa + 40); qb = ld64(pa + 41);
      qc = ld64(pa + 48); qd = ld64(pa + 49);
      qe = ld64(pa + 56); qf = ld64(pa + 57);
      u64t m = q0 | q1 | q2 | q3 | q4 | q5 | q6 | q7 |
               q8 | q9 | qa | qb | qc | qd | qe | qf;
      if (__all((m & TAGMASK) == 0ull)) break;
    }
    const int c0o = s * 16;
    f32x4 o0 = zero4;
    const float* pwo = Who + (size_t)(c0o + lr) * H_ + w * 256 + kg * 8;
    bf16x8 h0v = mk8(q0, q1), h1v = mk8(q2, q3);
    bf16x8 h2v = mk8(q4, q5), h3v = mk8(q6, q7);
    bf16x8 h4v = mk8(q8, q9), h5v = mk8(qa, qb);
    bf16x8 h6v = mk8(qc, qd), h7v = mk8(qe, qf);
    o0 = MFMA(h0v, cvt8(pwo + 0), o0, 0, 0, 0);
    o0 = MFMA(h1v, cvt8(pwo + 32), o0, 0, 0, 0);
    o0 = MFMA(h2v, cvt8(pwo + 64), o0, 0, 0, 0);
    o0 = MFMA(h3v, cvt8(pwo + 96), o0, 0, 0, 0);
    o0 = MFMA(h4v, cvt8(pwo + 128), o0, 0, 0, 0);
    o0 = MFMA(h5v, cvt8(pwo + 160), o0, 0, 0, 0);
    o0 = MFMA(h6v, cvt8(pwo + 192), o0, 0, 0, 0);
    o0 = MFMA(h7v, cvt8(pwo + 224), o0, 0, 0, 0);
    *(f32x4*)&red[(w * 64 + lane) * 9] = o0;
    __syncthreads();
    const int cc = tid & 15;
    const int l0 = lane_r | cc;
    float v = 0.f;
#pragma unroll
    for (int ww = 0; ww < 4; ++ww) v += red[(ww * 64 + l0) * 9 + reg_r];
    v += bho[c0o + cc];
    out[(size_t)(r0 + rr) * O_ + c0o + cc] = v;
  }
}

extern "C" void kernel_launch(void* const* d_in, const int* in_sizes, int n_in,
                              void* d_out, int out_size, void* d_ws,
                              size_t ws_size, hipStream_t stream) {
  const float* x = (const float*)d_in[0];
  const float* Wih = (const float*)d_in[1];
  const float* bih = (const float*)d_in[2];
  const float* Whh = (const float*)d_in[3];
  const float* bhh = (const float*)d_in[4];
  const float* Who = (const float*)d_in[5];
  const float* bho = (const float*)d_in[6];
  float* outp = (float*)d_out;

  char* ws = (char*)d_ws;
  u16* h0b = (u16*)ws;                        // 256 KB, holds h_even
  u16* h1b = (u16*)(ws + B_ * H_ * 2);        // 256 KB, holds h_odd

  // h_0 = zeros, tag 0 (valid immediately). h1b = 0xFF: fails tag-0 check
  // for h_1 until truly written (0xFFFF has sign bit 1).
  hipMemsetAsync(h0b, 0x00, B_ * H_ * 2, stream);
  hipMemsetAsync(h1b, 0xFF, B_ * H_ * 2, stream);

  void* args[] = {(void*)&x,   (void*)&Wih, (void*)&bih, (void*)&Whh,
                  (void*)&bhh, (void*)&Who, (void*)&bho, (void*)&h0b,
                  (void*)&h1b, (void*)&outp};
  hipLaunchCooperativeKernel((void*)rnn_persist, dim3(NBLK), dim3(256), args,
                             0, stream);
}

// Round 8
// 3311.947 us; speedup vs baseline: 5.0204x; 1.2249x over previous
//
#include <hip/hip_runtime.h>
#include <hip/hip_bf16.h>

#define B_ 128
#define T_ 1024
#define I_ 512
#define H_ 1024
#define O_ 512
#define NBLK 256

typedef __attribute__((ext_vector_type(8))) short bf16x8;
typedef __attribute__((ext_vector_type(4))) float f32x4;
typedef __attribute__((ext_vector_type(4))) unsigned u32x4;
typedef unsigned short u16;

__device__ __forceinline__ unsigned f2bf_u(float f) {
  union { float f; unsigned u; } v; v.f = f;
  return (v.u + 0x7fffu + ((v.u >> 16) & 1u)) >> 16;  // RNE bf16
}

__device__ __forceinline__ bf16x8 cvt8(const float* __restrict__ p) {
  union { bf16x8 v; unsigned u[4]; } r;
  const float4 f0 = *(const float4*)p;
  const float4 f1 = *(const float4*)(p + 4);
  r.u[0] = f2bf_u(f0.x) | (f2bf_u(f0.y) << 16);
  r.u[1] = f2bf_u(f0.z) | (f2bf_u(f0.w) << 16);
  r.u[2] = f2bf_u(f1.x) | (f2bf_u(f1.y) << 16);
  r.u[3] = f2bf_u(f1.z) | (f2bf_u(f1.w) << 16);
  return r.v;
}

__device__ __forceinline__ bf16x8 cvt8r(float4 f0, float4 f1) {
  union { bf16x8 v; unsigned u[4]; } r;
  r.u[0] = f2bf_u(f0.x) | (f2bf_u(f0.y) << 16);
  r.u[1] = f2bf_u(f0.z) | (f2bf_u(f0.w) << 16);
  r.u[2] = f2bf_u(f1.x) | (f2bf_u(f1.y) << 16);
  r.u[3] = f2bf_u(f1.z) | (f2bf_u(f1.w) << 16);
  return r.v;
}

// strip generation-tag sign bits -> valid bf16x8 fragment
__device__ __forceinline__ bf16x8 mk8v(u32x4 t) {
  union { u32x4 u; bf16x8 b; } v;
  v.u = t & 0x7fff7fffu;
  return v.b;
}

// coherent 16B load (bypass L1+L2, served at L3/coherence point)
#define LDT(dst, base, off)                                              \
  asm volatile("global_load_dwordx4 %0, %1, off offset:" #off " sc0 sc1" \
               : "=v"(dst) : "v"(base))

#define MFMA __builtin_amdgcn_mfma_f32_16x16x32_bf16

// Persistent RNN. Grid = 256 blocks x 256 threads (4 waves), 1 block/CU.
// Group g = blockIdx>>5 (16 batch rows); slot s = blockIdx&31 (32 hidden cols).
// h exchange layout: h_ex[g][s][row16][col32] -> each producer tile is one
// contiguous 1 KB block. A wave's poll = 8 coalesced dwordx4 loads that ARE
// the MFMA A-fragments (lane (lr,kg) reads tile byte lr*64+kg*16).
// Generation tag ((step>>1)&1) lives in the (always 0 after relu) bf16 sign
// bits; per-word check => tearing-safe; monotone => deadlock-free.
__global__ __launch_bounds__(256, 1) void rnn_persist(
    const float* __restrict__ x, const float* __restrict__ Wih,
    const float* __restrict__ bih, const float* __restrict__ Whh,
    const float* __restrict__ bhh, const float* __restrict__ Who,
    const float* __restrict__ bho, u16* __restrict__ h0buf,
    u16* __restrict__ h1buf, float* __restrict__ out) {
  __shared__ u16 w_lds[192 * 32 * 8];  // 96 KB: [k-octet o][col c][8 bf16]
  __shared__ float red[2][256 * 9];    // 18 KB double-buffered reduce scratch
  __shared__ float bias_lds[32];

  const int tid = threadIdx.x;
  const int w = tid >> 6;
  const int lane = tid & 63;
  const int lr = lane & 15;
  const int kg = lane >> 4;
  const int g = (int)blockIdx.x >> 5;
  const int s = (int)blockIdx.x & 31;
  const int r0 = g * 16;
  const int c0 = s * 32;

  // ---- stage W tile [32 cols x 1536 K] into LDS ----
  for (int e = tid; e < 192 * 32; e += 256) {
    int o = e >> 5, c = e & 31;
    int k = o * 8, gc = c0 + c;
    const float* src = (k < H_) ? (Whh + (size_t)gc * H_ + k)
                                : (Wih + (size_t)gc * I_ + (k - H_));
    *(bf16x8*)&w_lds[e * 8] = cvt8(src);
  }
  if (tid < 32) bias_lds[tid] = bih[c0 + tid] + bhh[c0 + tid];
  __syncthreads();

  // LDS fragment bases (u16 units)
  const u16* wb_h = &w_lds[(((w * 32 + kg) * 32) + lr) * 8];
  const u16* wb_x = &w_lds[(((128 + w * 16 + kg) * 32) + lr) * 8];

  // per-lane offset inside a producer tile: row lr, k-octet kg (u16 units)
  const int loff = lr * 32 + kg * 8;
  // this wave consumes producer tiles w*8 .. w*8+7 of its group
  const size_t twave = ((size_t)(g * 32 + w * 8)) * 512;
  // this block produces tile (g,s); thread tid owns dword tid of it
  const size_t towndw = ((size_t)(g * 32 + s)) * 256 + tid;

  // reduce/store thread mapping (same as r7, verified)
  const int rr = tid >> 4;           // row 0..15
  const int cpair = (tid & 15) * 2;  // col pair 0,2,..,30
  const int lane_r = (rr >> 2) << 4;
  const int reg_r = rr & 3;

  const f32x4 zero4 = {0.f, 0.f, 0.f, 0.f};
  f32x4 acc0, acc1;

  // ---- prologue: x-part for t=0 into acc ----
  {
    const float* px = x + ((size_t)(r0 + lr) * T_) * I_ + w * 128 + kg * 8;
    acc0 = zero4;
    acc1 = zero4;
#pragma unroll
    for (int i = 0; i < 4; ++i) {
      bf16x8 a = cvt8(px + i * 32);
      acc0 = MFMA(a, *(const bf16x8*)(wb_x + i * 1024), acc0, 0, 0, 0);
      acc1 = MFMA(a, *(const bf16x8*)(wb_x + i * 1024 + 128), acc1, 0, 0, 0);
    }
  }

  for (int t = 0; t < T_; ++t) {
    const u16* hc = (t & 1) ? h1buf : h0buf;
    u16* hn = (t & 1) ? h0buf : h1buf;
    const bool havex = (t + 1 < T_);

    u32x4 t0, t1, t2, t3, t4, t5, t6, t7;

    // 1: tag-poll h_t — 8 coalesced 16B loads that ARE the A-fragments
    if (t > 0) {
      const unsigned tw = ((t >> 1) & 1) ? 0x80008000u : 0u;
      const u16* tb0 = hc + twave + loff;
      const u16* tb4 = tb0 + 4 * 512;
      for (;;) {
        LDT(t0, tb0, 0);
        LDT(t1, tb0, 1024);
        LDT(t2, tb0, 2048);
        LDT(t3, tb0, 3072);
        LDT(t4, tb4, 0);
        LDT(t5, tb4, 1024);
        LDT(t6, tb4, 2048);
        LDT(t7, tb4, 3072);
        asm volatile("s_waitcnt vmcnt(0)" ::: "memory");
        __builtin_amdgcn_sched_barrier(0);
        u32x4 m4 = (t0 ^ tw) | (t1 ^ tw) | (t2 ^ tw) | (t3 ^ tw) |
                   (t4 ^ tw) | (t5 ^ tw) | (t6 ^ tw) | (t7 ^ tw);
        unsigned mm = m4.x | m4.y | m4.z | m4.w;
        if (__all((mm & 0x80008000u) == 0u)) break;
      }
    }

    // 2: issue x loads for t+1 (after poll: never in the poll's vmcnt shadow)
    float4 xa0, xa1, xa2, xa3, xa4, xa5, xa6, xa7;
    const float* px =
        x + ((size_t)(r0 + lr) * T_ + (t + 1)) * I_ + w * 128 + kg * 8;
    if (havex) {
      xa0 = *(const float4*)(px);      xa1 = *(const float4*)(px + 4);
      xa2 = *(const float4*)(px + 32); xa3 = *(const float4*)(px + 36);
      xa4 = *(const float4*)(px + 64); xa5 = *(const float4*)(px + 68);
      xa6 = *(const float4*)(px + 96); xa7 = *(const float4*)(px + 100);
    }

    // 3: h-part MFMAs (fragments already laid out correctly)
    if (t > 0) {
#define HS(i, tv)                                                         \
  acc0 = MFMA(mk8v(tv), *(const bf16x8*)(wb_h + (i)*1024), acc0, 0, 0, 0); \
  acc1 = MFMA(mk8v(tv), *(const bf16x8*)(wb_h + (i)*1024 + 128), acc1, 0, 0, 0);
      HS(0, t0) HS(1, t1) HS(2, t2) HS(3, t3)
      HS(4, t4) HS(5, t5) HS(6, t6) HS(7, t7)
#undef HS
    }

    // 4: cross-wave K-reduce, bias+relu, pack + tag, contiguous sc1 store
    float* redc = red[t & 1];
    *(f32x4*)&redc[(w * 64 + lane) * 9] = acc0;
    *(f32x4*)&redc[(w * 64 + lane) * 9 + 4] = acc1;
    __syncthreads();
    {
      const unsigned st = (((t + 1) >> 1) & 1) ? 0x80008000u : 0u;
      const int c1 = cpair + 1;
      const int l0 = lane_r | (cpair & 15), f0 = (cpair >> 4) * 4;
      const int l1 = lane_r | (c1 & 15), f1 = (c1 >> 4) * 4;
      float v0 = 0.f, v1 = 0.f;
#pragma unroll
      for (int ww = 0; ww < 4; ++ww) {
        v0 += redc[(ww * 64 + l0) * 9 + f0 + reg_r];
        v1 += redc[(ww * 64 + l1) * 9 + f1 + reg_r];
      }
      v0 += bias_lds[cpair];
      v1 += bias_lds[c1];
      v0 = v0 > 0.f ? v0 : 0.f;
      v1 = v1 > 0.f ? v1 : 0.f;
      unsigned pk = (f2bf_u(v0) | (f2bf_u(v1) << 16)) | st;
      __hip_atomic_store((unsigned*)hn + towndw, pk, __ATOMIC_RELAXED,
                         __HIP_MEMORY_SCOPE_AGENT);
    }

    // 5: x-part for t+1 (off critical path; overlaps consumers' polls)
    f32x4 xacc0 = zero4, xacc1 = zero4;
    if (havex) {
      bf16x8 a0 = cvt8r(xa0, xa1), a1 = cvt8r(xa2, xa3);
      bf16x8 a2 = cvt8r(xa4, xa5), a3 = cvt8r(xa6, xa7);
      xacc0 = MFMA(a0, *(const bf16x8*)(wb_x), xacc0, 0, 0, 0);
      xacc1 = MFMA(a0, *(const bf16x8*)(wb_x + 128), xacc1, 0, 0, 0);
      xacc0 = MFMA(a1, *(const bf16x8*)(wb_x + 1024), xacc0, 0, 0, 0);
      xacc1 = MFMA(a1, *(const bf16x8*)(wb_x + 1152), xacc1, 0, 0, 0);
      xacc0 = MFMA(a2, *(const bf16x8*)(wb_x + 2048), xacc0, 0, 0, 0);
      xacc1 = MFMA(a2, *(const bf16x8*)(wb_x + 2176), xacc1, 0, 0, 0);
      xacc0 = MFMA(a3, *(const bf16x8*)(wb_x + 3072), xacc0, 0, 0, 0);
      xacc1 = MFMA(a3, *(const bf16x8*)(wb_x + 3200), xacc1, 0, 0, 0);
    }
    acc0 = xacc0;
    acc1 = xacc1;
  }

  // ---- output GEMM: poll h_T (tag 0), out = h @ Who^T + bho ----
  {
    u32x4 t0, t1, t2, t3, t4, t5, t6, t7;
    const u16* tb0 = h0buf + twave + loff;
    const u16* tb4 = tb0 + 4 * 512;
    for (;;) {
      LDT(t0, tb0, 0);
      LDT(t1, tb0, 1024);
      LDT(t2, tb0, 2048);
      LDT(t3, tb0, 3072);
      LDT(t4, tb4, 0);
      LDT(t5, tb4, 1024);
      LDT(t6, tb4, 2048);
      LDT(t7, tb4, 3072);
      asm volatile("s_waitcnt vmcnt(0)" ::: "memory");
      __builtin_amdgcn_sched_barrier(0);
      u32x4 m4 = t0 | t1 | t2 | t3 | t4 | t5 | t6 | t7;
      unsigned mm = m4.x | m4.y | m4.z | m4.w;
      if (__all((mm & 0x80008000u) == 0u)) break;
    }
    const int c0o = s * 16;
    f32x4 o0 = zero4;
    const float* pwo = Who + (size_t)(c0o + lr) * H_ + w * 256 + kg * 8;
    o0 = MFMA(mk8v(t0), cvt8(pwo + 0), o0, 0, 0, 0);
    o0 = MFMA(mk8v(t1), cvt8(pwo + 32), o0, 0, 0, 0);
    o0 = MFMA(mk8v(t2), cvt8(pwo + 64), o0, 0, 0, 0);
    o0 = MFMA(mk8v(t3), cvt8(pwo + 96), o0, 0, 0, 0);
    o0 = MFMA(mk8v(t4), cvt8(pwo + 128), o0, 0, 0, 0);
    o0 = MFMA(mk8v(t5), cvt8(pwo + 160), o0, 0, 0, 0);
    o0 = MFMA(mk8v(t6), cvt8(pwo + 192), o0, 0, 0, 0);
    o0 = MFMA(mk8v(t7), cvt8(pwo + 224), o0, 0, 0, 0);
    float* redc = red[0];
    *(f32x4*)&redc[(w * 64 + lane) * 9] = o0;
    __syncthreads();
    const int cc = tid & 15;
    const int l0 = lane_r | cc;
    float v = 0.f;
#pragma unroll
    for (int ww = 0; ww < 4; ++ww) v += redc[(ww * 64 + l0) * 9 + reg_r];
    v += bho[c0o + cc];
    out[(size_t)(r0 + rr) * O_ + c0o + cc] = v;
  }
}

extern "C" void kernel_launch(void* const* d_in, const int* in_sizes, int n_in,
                              void* d_out, int out_size, void* d_ws,
                              size_t ws_size, hipStream_t stream) {
  const float* x = (const float*)d_in[0];
  const float* Wih = (const float*)d_in[1];
  const float* bih = (const float*)d_in[2];
  const float* Whh = (const float*)d_in[3];
  const float* bhh = (const float*)d_in[4];
  const float* Who = (const float*)d_in[5];
  const float* bho = (const float*)d_in[6];
  float* outp = (float*)d_out;

  char* ws = (char*)d_ws;
  u16* h0b = (u16*)ws;                        // 256 KB, h_even (tile layout)
  u16* h1b = (u16*)(ws + B_ * H_ * 2);        // 256 KB, h_odd

  // h_0 = zeros with tag 0 (immediately valid). h1b = 0xFF: sign bits 1 =>
  // fails the tag-0 check for h_1 until truly written.
  hipMemsetAsync(h0b, 0x00, B_ * H_ * 2, stream);
  hipMemsetAsync(h1b, 0xFF, B_ * H_ * 2, stream);

  void* args[] = {(void*)&x,   (void*)&Wih, (void*)&bih, (void*)&Whh,
                  (void*)&bhh, (void*)&Who, (void*)&bho, (void*)&h0b,
                  (void*)&h1b, (void*)&outp};
  hipLaunchCooperativeKernel((void*)rnn_persist, dim3(NBLK), dim3(256), args,
                             0, stream);
}